// Round 1
// baseline (432.674 us; speedup 1.0000x reference)
//
#include <hip/hip_runtime.h>

// Problem collapse (see analysis): T=1, H=1, h0=c0=0 =>
//   - Wh weights and f-gate are dead.
//   - conv (kh,1) over H=1 SAME => pointwise matmul with Wx[(kh-1)//2, 0, :, :].
// Pipeline: 4x gated pointwise 64->192 matmul over 131072 positions,
// then y=relu(flat(64x131072) @ D1w) , out = y @ D2w + D2b.

#define POS 131072          // 64 * 2048 positions
#define LAYER_BLOCKS 512    // POS / 256

__device__ __forceinline__ float hsig(float x) {
    return fminf(fmaxf(fmaf(x, 0.2f, 0.5f), 0.0f), 1.0f);
}

__device__ __forceinline__ float tanh_fast(float x) {
    // |x| < 0.04: series (avoids 1 - (1-x) cancellation); else exp form.
    float x2 = x * x;
    float e = __expf(2.0f * x);
    float big = 1.0f - __fdividef(2.0f, e + 1.0f);
    float small = x * fmaf(x2, -0.33333333333f, 1.0f);
    return (x2 < 0.0016f) ? small : big;
}

// One ConvLSTM layer: hout[p][j] = hs(z_o)*tanh( hs(z_i)*tanh(z_g) )
// z_g* from 64->192 matvec. W points at Wx + pad_lo*64*256 (layout (c,256)).
__global__ __launch_bounds__(256) void lstm_layer(
    const float* __restrict__ hin, const float* __restrict__ W,
    const float* __restrict__ bias, float* __restrict__ hout)
{
    __shared__ float Ws[3][64][64];   // [gate i/g/o][c][j]
    __shared__ float bs[3][64];
    const int tid = threadIdx.x;

    for (int idx = tid; idx < 3 * 64 * 64; idx += 256) {
        int gate = idx >> 12;
        int rem  = idx & 4095;
        int c = rem >> 6;
        int j = rem & 63;
        int zj = (gate == 0) ? j : ((gate == 1) ? (128 + j) : (192 + j));
        Ws[gate][c][j] = W[c * 256 + zj];
    }
    if (tid < 192) {
        int gate = tid >> 6;
        int j = tid & 63;
        int zj = (gate == 0) ? j : ((gate == 1) ? (128 + j) : (192 + j));
        bs[gate][j] = bias[zj];
    }
    __syncthreads();

    const int p = blockIdx.x * 256 + tid;
    const float4* hv = (const float4*)(hin + (size_t)p * 64);
    float h[64];
    #pragma unroll
    for (int i = 0; i < 16; i++) {
        float4 v = hv[i];
        h[4*i+0] = v.x; h[4*i+1] = v.y; h[4*i+2] = v.z; h[4*i+3] = v.w;
    }

    float4* ho = (float4*)(hout + (size_t)p * 64);
    #pragma unroll 1
    for (int j0 = 0; j0 < 64; j0 += 4) {
        float zi[4], zg[4], zo[4];
        #pragma unroll
        for (int q = 0; q < 4; q++) {
            zi[q] = bs[0][j0 + q];
            zg[q] = bs[1][j0 + q];
            zo[q] = bs[2][j0 + q];
        }
        #pragma unroll
        for (int c = 0; c < 64; c++) {
            float hc = h[c];
            #pragma unroll
            for (int q = 0; q < 4; q++) {
                zi[q] = fmaf(hc, Ws[0][c][j0 + q], zi[q]);
                zg[q] = fmaf(hc, Ws[1][c][j0 + q], zg[q]);
                zo[q] = fmaf(hc, Ws[2][c][j0 + q], zo[q]);
            }
        }
        float4 res;
        float* rp = (float*)&res;
        #pragma unroll
        for (int q = 0; q < 4; q++) {
            float cs = hsig(zi[q]) * tanh_fast(zg[q]);
            rp[q]    = hsig(zo[q]) * tanh_fast(cs);
        }
        ho[j0 >> 2] = res;
    }
}

// Partial GEMM: C[b][j] = sum_k A[b][k]*Bw[k][j], K split over 512 blocks of 256.
// A = h4 viewed as (64, 131072) row-major; Bw = D1w (131072, 64).
__global__ __launch_bounds__(256) void d1_partial(
    const float* __restrict__ A, const float* __restrict__ Bw,
    float* __restrict__ part)
{
    __shared__ float As[64][65];   // [b][kk], padded
    __shared__ float Bs[64][64];   // [kk][j]
    const int t  = threadIdx.x;
    const int kb = blockIdx.x;
    const int tx = t & 15, ty = t >> 4;

    float acc[4][4];
    #pragma unroll
    for (int i = 0; i < 4; i++)
        #pragma unroll
        for (int j = 0; j < 4; j++) acc[i][j] = 0.0f;

    for (int kc = 0; kc < 4; kc++) {
        const int k0 = kb * 256 + kc * 64;
        __syncthreads();
        #pragma unroll
        for (int i = 0; i < 16; i++) {
            int b  = (t >> 6) + 4 * i;
            int kk = t & 63;
            As[b][kk] = A[(size_t)b * 131072 + k0 + kk];
        }
        #pragma unroll
        for (int i = 0; i < 16; i++) {
            int kk = (t >> 6) + 4 * i;
            int j  = t & 63;
            Bs[kk][j] = Bw[(size_t)(k0 + kk) * 64 + j];
        }
        __syncthreads();
        #pragma unroll 8
        for (int kk = 0; kk < 64; kk++) {
            float a0 = As[4*ty+0][kk], a1 = As[4*ty+1][kk];
            float a2 = As[4*ty+2][kk], a3 = As[4*ty+3][kk];
            float b0 = Bs[kk][4*tx+0], b1 = Bs[kk][4*tx+1];
            float b2 = Bs[kk][4*tx+2], b3 = Bs[kk][4*tx+3];
            acc[0][0] = fmaf(a0, b0, acc[0][0]); acc[0][1] = fmaf(a0, b1, acc[0][1]);
            acc[0][2] = fmaf(a0, b2, acc[0][2]); acc[0][3] = fmaf(a0, b3, acc[0][3]);
            acc[1][0] = fmaf(a1, b0, acc[1][0]); acc[1][1] = fmaf(a1, b1, acc[1][1]);
            acc[1][2] = fmaf(a1, b2, acc[1][2]); acc[1][3] = fmaf(a1, b3, acc[1][3]);
            acc[2][0] = fmaf(a2, b0, acc[2][0]); acc[2][1] = fmaf(a2, b1, acc[2][1]);
            acc[2][2] = fmaf(a2, b2, acc[2][2]); acc[2][3] = fmaf(a2, b3, acc[2][3]);
            acc[3][0] = fmaf(a3, b0, acc[3][0]); acc[3][1] = fmaf(a3, b1, acc[3][1]);
            acc[3][2] = fmaf(a3, b2, acc[3][2]); acc[3][3] = fmaf(a3, b3, acc[3][3]);
        }
    }
    float* dst = part + (size_t)kb * 4096;
    #pragma unroll
    for (int i = 0; i < 4; i++)
        #pragma unroll
        for (int j = 0; j < 4; j++)
            dst[(4*ty+i)*64 + 4*tx + j] = acc[i][j];
}

// Reduce 512 partials, + D1b, relu, dot with D2w, + D2b.
__global__ __launch_bounds__(64) void d1_reduce(
    const float* __restrict__ part, const float* __restrict__ D1b,
    const float* __restrict__ D2w, const float* __restrict__ D2b,
    float* __restrict__ out)
{
    const int b = blockIdx.x;
    const int j = threadIdx.x;
    float acc = 0.0f;
    for (int kb = 0; kb < 512; kb++)
        acc += part[(size_t)kb * 4096 + b * 64 + j];
    acc += D1b[j];
    acc = fmaxf(acc, 0.0f);
    float v = acc * D2w[j];
    #pragma unroll
    for (int off = 32; off > 0; off >>= 1)
        v += __shfl_down(v, off, 64);
    if (j == 0) out[b] = v + D2b[0];
}

extern "C" void kernel_launch(void* const* d_in, const int* in_sizes, int n_in,
                              void* d_out, int out_size, void* d_ws, size_t ws_size,
                              hipStream_t stream) {
    (void)in_sizes; (void)n_in; (void)out_size; (void)ws_size;
    const float* x   = (const float*)d_in[0];
    const float* W1x = (const float*)d_in[1];
    const float* b1  = (const float*)d_in[3];
    const float* W2x = (const float*)d_in[4];
    const float* b2  = (const float*)d_in[6];
    const float* W3x = (const float*)d_in[7];
    const float* b3  = (const float*)d_in[9];
    const float* W4x = (const float*)d_in[10];
    const float* b4  = (const float*)d_in[12];
    const float* D1w = (const float*)d_in[13];
    const float* D1b = (const float*)d_in[14];
    const float* D2w = (const float*)d_in[15];
    const float* D2b = (const float*)d_in[16];
    float* out = (float*)d_out;

    float* hA   = (float*)d_ws;            // 8388608 floats = 32 MB
    float* hB   = hA + (size_t)POS * 64;   // 32 MB
    float* part = hB + (size_t)POS * 64;   // 512*4096 floats = 8 MB

    // Effective weight row: pad_lo = (kh-1)/2 -> row 4 (kh=10), row 2 (kh=5).
    // Row stride in Wx = 64*256 = 16384 floats.
    lstm_layer<<<dim3(LAYER_BLOCKS), dim3(256), 0, stream>>>(x,  W1x + 4 * 16384, b1, hA);
    lstm_layer<<<dim3(LAYER_BLOCKS), dim3(256), 0, stream>>>(hA, W2x + 2 * 16384, b2, hB);
    lstm_layer<<<dim3(LAYER_BLOCKS), dim3(256), 0, stream>>>(hB, W3x + 4 * 16384, b3, hA);
    lstm_layer<<<dim3(LAYER_BLOCKS), dim3(256), 0, stream>>>(hA, W4x + 2 * 16384, b4, hB);
    d1_partial<<<dim3(512), dim3(256), 0, stream>>>(hB, D1w, part);
    d1_reduce<<<dim3(64), dim3(64), 0, stream>>>(part, D1b, D2w, D2b, out);
}

// Round 2
// 356.028 us; speedup vs baseline: 1.2153x; 1.2153x over previous
//
#include <hip/hip_runtime.h>

// Problem collapse: T=1, H=1, h0=c0=0 =>
//   - Wh weights and f-gate dead; conv (kh,1) over H=1 SAME => pointwise
//     matmul with Wx[(kh-1)//2, 0, :, :] (row 4 for kh=10, row 2 for kh=5).
//   - All 4 layers are per-position => fully fused in one kernel, h in LDS.
// Then y = relu(flat(64x131072) @ D1w) @ D2w + D2b.

#define POS 131072
#define PADP 68   // padded position-stride (16B-aligned rows, breaks 16-way write conflicts)

__device__ __forceinline__ float hsig(float x) {
    return fminf(fmaxf(fmaf(x, 0.2f, 0.5f), 0.0f), 1.0f);
}

__device__ __forceinline__ float tanh_fast(float x) {
    float x2 = x * x;
    float e = __expf(2.0f * x);
    float big = 1.0f - __fdividef(2.0f, e + 1.0f);
    float small = x * fmaf(x2, -0.33333333333f, 1.0f);
    return (x2 < 0.0016f) ? small : big;
}

// All 4 gated pointwise layers fused. Block = 64 positions.
// Hc: transposed h tile [c][p]. Ws/bs restaged per layer (L2-resident).
__global__ __launch_bounds__(256, 2) void fused_layers(
    const float* __restrict__ x,
    const float* __restrict__ W1, const float* __restrict__ B1,
    const float* __restrict__ W2, const float* __restrict__ B2,
    const float* __restrict__ W3, const float* __restrict__ B3,
    const float* __restrict__ W4, const float* __restrict__ B4,
    float* __restrict__ hout)
{
    __shared__ float Hc[64][PADP];    // ~17.4 KB
    __shared__ float Ws[3][64][64];   // 48 KB  [gate i/g/o][c][j]
    __shared__ float bs[3][64];

    const int t = threadIdx.x;
    const int tx = t & 15, ty = t >> 4;
    const size_t base = (size_t)blockIdx.x * 64 * 64;   // floats

    const float* Wl[4] = {W1, W2, W3, W4};
    const float* Bl[4] = {B1, B2, B3, B4};

    auto stage_w = [&](const float* W, const float* B) {
        #pragma unroll
        for (int k = 0; k < 12; k++) {
            int idx4 = t + k * 256;          // float4 id in 3*64*16
            int g = idx4 >> 10;
            int rem = idx4 & 1023;
            int c = rem >> 4;
            int j4 = (rem & 15) * 4;
            int gofs = (g == 0) ? 0 : ((g == 1) ? 128 : 192);
            float4 v = *(const float4*)(W + c * 256 + gofs + j4);
            *(float4*)&Ws[g][c][j4] = v;
        }
        if (t < 192) {
            int g = t >> 6, j = t & 63;
            int gofs = (g == 0) ? 0 : ((g == 1) ? 128 : 192);
            bs[g][j] = B[gofs + j];
        }
    };

    // Prologue: stage x -> Hc (transposed), stage layer-1 weights.
    {
        const float4* xv = (const float4*)(x + base);
        #pragma unroll
        for (int k = 0; k < 4; k++) {
            int lin4 = t + k * 256;          // float4 id in 64x64 tile
            float4 v = xv[lin4];
            int p = lin4 >> 4;
            int c0 = (lin4 & 15) * 4;
            Hc[c0 + 0][p] = v.x; Hc[c0 + 1][p] = v.y;
            Hc[c0 + 2][p] = v.z; Hc[c0 + 3][p] = v.w;
        }
    }
    stage_w(Wl[0], Bl[0]);
    __syncthreads();

    #pragma unroll 1
    for (int l = 0; l < 4; l++) {
        float zi[4][4], zg[4][4], zo[4][4];  // [pos i][out q]
        #pragma unroll
        for (int i = 0; i < 4; i++)
            #pragma unroll
            for (int q = 0; q < 4; q++) {
                zi[i][q] = bs[0][4 * tx + q];
                zg[i][q] = bs[1][4 * tx + q];
                zo[i][q] = bs[2][4 * tx + q];
            }
        #pragma unroll 4
        for (int c = 0; c < 64; c++) {
            float4 a  = *(const float4*)&Hc[c][4 * ty];
            float4 wi = *(const float4*)&Ws[0][c][4 * tx];
            float4 wg = *(const float4*)&Ws[1][c][4 * tx];
            float4 wo = *(const float4*)&Ws[2][c][4 * tx];
            const float* ap  = (const float*)&a;
            const float* wip = (const float*)&wi;
            const float* wgp = (const float*)&wg;
            const float* wop = (const float*)&wo;
            #pragma unroll
            for (int i = 0; i < 4; i++)
                #pragma unroll
                for (int q = 0; q < 4; q++) {
                    zi[i][q] = fmaf(ap[i], wip[q], zi[i][q]);
                    zg[i][q] = fmaf(ap[i], wgp[q], zg[i][q]);
                    zo[i][q] = fmaf(ap[i], wop[q], zo[i][q]);
                }
        }
        __syncthreads();   // all reads of Hc/Ws done -> safe to overwrite
        #pragma unroll
        for (int q = 0; q < 4; q++) {
            float4 hv;
            float* hp = (float*)&hv;
            #pragma unroll
            for (int i = 0; i < 4; i++) {
                float cs = hsig(zi[i][q]) * tanh_fast(zg[i][q]);
                hp[i]    = hsig(zo[i][q]) * tanh_fast(cs);
            }
            *(float4*)&Hc[4 * tx + q][4 * ty] = hv;   // in-place: own columns only
        }
        if (l < 3) stage_w(Wl[l + 1], Bl[l + 1]);
        __syncthreads();
    }

    // Coalesced writeout: Hc (transposed) -> hout (pos, 64)
    {
        float4* ov = (float4*)(hout + base);
        #pragma unroll
        for (int k = 0; k < 4; k++) {
            int lin4 = t + k * 256;
            int p = lin4 >> 4;
            int c0 = (lin4 & 15) * 4;
            ov[lin4] = make_float4(Hc[c0][p], Hc[c0 + 1][p],
                                   Hc[c0 + 2][p], Hc[c0 + 3][p]);
        }
    }
}

// Partial GEMM: C[b][j] = sum_k A[b][k]*Bw[k][j]; K split over 512 blocks.
__global__ __launch_bounds__(256) void d1_partial(
    const float* __restrict__ A, const float* __restrict__ Bw,
    float* __restrict__ part)
{
    __shared__ float As[64][68];   // [kk][b], padded, b128-readable
    __shared__ float Bs[64][64];   // [kk][j]
    const int t = threadIdx.x;
    const int kb = blockIdx.x;
    const int tx = t & 15, ty = t >> 4;

    float acc[4][4];
    #pragma unroll
    for (int i = 0; i < 4; i++)
        #pragma unroll
        for (int j = 0; j < 4; j++) acc[i][j] = 0.0f;

    for (int kc = 0; kc < 4; kc++) {
        const int k0 = kb * 256 + kc * 64;
        __syncthreads();
        #pragma unroll
        for (int i = 0; i < 16; i++) {
            int b  = (t >> 6) + 4 * i;
            int kk = t & 63;
            As[kk][b] = A[(size_t)b * 131072 + k0 + kk];
        }
        #pragma unroll
        for (int k = 0; k < 4; k++) {
            int idx4 = t + k * 256;
            int kk = idx4 >> 4;
            int j4 = (idx4 & 15) * 4;
            *(float4*)&Bs[kk][j4] = *(const float4*)(Bw + (size_t)(k0 + kk) * 64 + j4);
        }
        __syncthreads();
        #pragma unroll 8
        for (int kk = 0; kk < 64; kk++) {
            float4 av = *(const float4*)&As[kk][4 * ty];
            float4 bv = *(const float4*)&Bs[kk][4 * tx];
            const float* ap = (const float*)&av;
            const float* bp = (const float*)&bv;
            #pragma unroll
            for (int i = 0; i < 4; i++)
                #pragma unroll
                for (int j = 0; j < 4; j++)
                    acc[i][j] = fmaf(ap[i], bp[j], acc[i][j]);
        }
    }
    float* dst = part + (size_t)kb * 4096;
    #pragma unroll
    for (int i = 0; i < 4; i++)
        #pragma unroll
        for (int j = 0; j < 4; j++)
            dst[(4 * ty + i) * 64 + 4 * tx + j] = acc[i][j];
}

// Reduce 512 partials, + D1b, relu, dot with D2w, + D2b.
__global__ __launch_bounds__(256) void d1_reduce(
    const float* __restrict__ part, const float* __restrict__ D1b,
    const float* __restrict__ D2w, const float* __restrict__ D2b,
    float* __restrict__ out)
{
    __shared__ float red[4][64];
    const int b = blockIdx.x;
    const int t = threadIdx.x;
    const int j = t & 63, s = t >> 6;
    float acc = 0.0f;
    for (int kb = s; kb < 512; kb += 4)
        acc += part[(size_t)kb * 4096 + b * 64 + j];
    red[s][j] = acc;
    __syncthreads();
    if (t < 64) {
        float v = red[0][t] + red[1][t] + red[2][t] + red[3][t] + D1b[t];
        v = fmaxf(v, 0.0f) * D2w[t];
        #pragma unroll
        for (int off = 32; off > 0; off >>= 1)
            v += __shfl_down(v, off, 64);
        if (t == 0) out[b] = v + D2b[0];
    }
}

extern "C" void kernel_launch(void* const* d_in, const int* in_sizes, int n_in,
                              void* d_out, int out_size, void* d_ws, size_t ws_size,
                              hipStream_t stream) {
    (void)in_sizes; (void)n_in; (void)out_size; (void)ws_size;
    const float* x   = (const float*)d_in[0];
    const float* W1x = (const float*)d_in[1];
    const float* b1  = (const float*)d_in[3];
    const float* W2x = (const float*)d_in[4];
    const float* b2  = (const float*)d_in[6];
    const float* W3x = (const float*)d_in[7];
    const float* b3  = (const float*)d_in[9];
    const float* W4x = (const float*)d_in[10];
    const float* b4  = (const float*)d_in[12];
    const float* D1w = (const float*)d_in[13];
    const float* D1b = (const float*)d_in[14];
    const float* D2w = (const float*)d_in[15];
    const float* D2b = (const float*)d_in[16];
    float* out = (float*)d_out;

    float* h4   = (float*)d_ws;            // 32 MB
    float* part = h4 + (size_t)POS * 64;   // 8 MB

    // Effective weight row: pad_lo = (kh-1)/2 -> row 4 (kh=10), row 2 (kh=5).
    fused_layers<<<dim3(POS / 64), dim3(256), 0, stream>>>(
        x, W1x + 4 * 16384, b1, W2x + 2 * 16384, b2,
           W3x + 4 * 16384, b3, W4x + 2 * 16384, b4, h4);
    d1_partial<<<dim3(512), dim3(256), 0, stream>>>(h4, D1w, part);
    d1_reduce<<<dim3(64), dim3(256), 0, stream>>>(part, D1b, D2w, D2b, out);
}

// Round 3
// 219.809 us; speedup vs baseline: 1.9684x; 1.6197x over previous
//
#include <hip/hip_runtime.h>

// Problem collapse: T=1, H=1, h0=c0=0 => Wh/f-gate dead; conv => pointwise
// matmul with Wx[(kh-1)//2,0,:,:]. 4 layers fused, split-bf16 MFMA
// (hi*hi + hi*lo + lo*hi, ~2^-18 rel err). Then D1/D2 dense tail.

#define POS 131072

typedef __attribute__((ext_vector_type(8))) short bf16x8;
typedef __attribute__((ext_vector_type(4))) float f32x4;

__device__ __forceinline__ unsigned short f2bf_rn(float f) {
    unsigned u = __float_as_uint(f);
    u += 0x7FFF + ((u >> 16) & 1);
    return (unsigned short)(u >> 16);
}
__device__ __forceinline__ float bf2f(unsigned short h) {
    return __uint_as_float(((unsigned)h) << 16);
}
__device__ __forceinline__ float hsig(float x) {
    return fminf(fmaxf(fmaf(x, 0.2f, 0.5f), 0.0f), 1.0f);
}
__device__ __forceinline__ float tanh_fast(float x) {
    float x2 = x * x;
    float e = __expf(2.0f * x);
    float big = 1.0f - __fdividef(2.0f, e + 1.0f);
    float small = x * fmaf(x2, -0.33333333333f, 1.0f);
    return (x2 < 0.0016f) ? small : big;
}

// Convert center-row weights to transposed split-bf16: per layer
// [hi: 192 rows x 64 c][lo: 192 x 64], row = g*64 + n (g in {i,g,o}).
// Grid 12 = 4 layers x 3 gates, 256 threads.
__global__ __launch_bounds__(256) void prep_w(
    const float* __restrict__ W1, const float* __restrict__ W2,
    const float* __restrict__ W3, const float* __restrict__ W4,
    unsigned short* __restrict__ WT)
{
    const int l = blockIdx.x >> 2;        // 0..2 -> wrong; use /3 mapping below
    // grid 12: bid = l*3 + g
    const int bid = blockIdx.x;
    const int ll = bid / 3;
    const int g  = bid - ll * 3;
    const float* W = (ll == 0) ? (W1 + 4 * 16384) :
                     (ll == 1) ? (W2 + 2 * 16384) :
                     (ll == 2) ? (W3 + 4 * 16384) : (W4 + 2 * 16384);
    const int gofs = (g == 0) ? 0 : ((g == 1) ? 128 : 192);
    unsigned short* hi = WT + ll * (2 * 192 * 64) + (g * 64) * 64;
    unsigned short* lo = hi + 192 * 64;
    const int n  = threadIdx.x & 63;
    const int c0 = threadIdx.x >> 6;
    (void)l;
    #pragma unroll
    for (int cc = 0; cc < 16; cc++) {
        int c = cc * 4 + c0;
        float w = W[c * 256 + gofs + n];
        unsigned short h = f2bf_rn(w);
        float rem = w - bf2f(h);
        hi[n * 64 + c] = h;
        lo[n * 64 + c] = f2bf_rn(rem);
    }
}

// Fused 4-layer gated pointwise stack, split-bf16 MFMA 16x16x32.
// Block = 64 positions, 4 waves; wave w owns output channels 16w..16w+15
// (gate tiles w / w+4 / w+8 -> i/g/o wave-local).
__global__ __launch_bounds__(256, 4) void fused_mfma(
    const float* __restrict__ x,
    const unsigned short* __restrict__ WT,
    const float* __restrict__ B1, const float* __restrict__ B2,
    const float* __restrict__ B3, const float* __restrict__ B4,
    float* __restrict__ h4)
{
    __shared__ unsigned short Hhi[64][72];   // stride 72 -> 2-way banks (free)
    __shared__ unsigned short Hlo[64][72];

    const int t = threadIdx.x;
    const int lane = t & 63;
    const int w = t >> 6;
    const int tx = lane & 15;
    const int quad = lane >> 4;
    const int n = 16 * w + tx;               // this lane's output channel
    const int pbase = blockIdx.x * 64;

    // Stage x -> split-bf16 LDS.
    {
        const float4* xv = (const float4*)(x + (size_t)pbase * 64);
        #pragma unroll
        for (int k = 0; k < 4; k++) {
            int lin4 = t + k * 256;          // float4 id in 64x64 tile
            int p = lin4 >> 4;
            int c0 = (lin4 & 15) * 4;
            float4 v = xv[lin4];
            const float* vp = (const float*)&v;
            unsigned hh01, hh23, ll01, ll23;
            unsigned short h0 = f2bf_rn(vp[0]), h1 = f2bf_rn(vp[1]);
            unsigned short h2 = f2bf_rn(vp[2]), h3 = f2bf_rn(vp[3]);
            hh01 = (unsigned)h0 | ((unsigned)h1 << 16);
            hh23 = (unsigned)h2 | ((unsigned)h3 << 16);
            ll01 = (unsigned)f2bf_rn(vp[0] - bf2f(h0)) |
                   ((unsigned)f2bf_rn(vp[1] - bf2f(h1)) << 16);
            ll23 = (unsigned)f2bf_rn(vp[2] - bf2f(h2)) |
                   ((unsigned)f2bf_rn(vp[3] - bf2f(h3)) << 16);
            *(uint2*)&Hhi[p][c0] = make_uint2(hh01, hh23);
            *(uint2*)&Hlo[p][c0] = make_uint2(ll01, ll23);
        }
    }
    __syncthreads();

    #pragma unroll
    for (int l = 0; l < 4; l++) {
        const unsigned short* wl = WT + l * (2 * 192 * 64);
        const float* Bb = (l == 0) ? B1 : (l == 1) ? B2 : (l == 2) ? B3 : B4;
        const float bi = Bb[n];
        const float bg = Bb[128 + n];
        const float bo = Bb[192 + n];

        f32x4 acc[4][3];
        #pragma unroll
        for (int m = 0; m < 4; m++) {
            acc[m][0] = (f32x4){bi, bi, bi, bi};
            acc[m][1] = (f32x4){bg, bg, bg, bg};
            acc[m][2] = (f32x4){bo, bo, bo, bo};
        }

        #pragma unroll
        for (int ks = 0; ks < 2; ks++) {
            bf16x8 Bh[3], Bl[3];
            #pragma unroll
            for (int g = 0; g < 3; g++) {
                const unsigned short* bp = wl + (g * 64 + n) * 64 + ks * 32 + quad * 8;
                Bh[g] = *(const bf16x8*)bp;
                Bl[g] = *(const bf16x8*)(bp + 192 * 64);
            }
            #pragma unroll
            for (int m = 0; m < 4; m++) {
                bf16x8 Ah = *(const bf16x8*)&Hhi[m * 16 + tx][ks * 32 + quad * 8];
                bf16x8 Al = *(const bf16x8*)&Hlo[m * 16 + tx][ks * 32 + quad * 8];
                #pragma unroll
                for (int g = 0; g < 3; g++) {
                    acc[m][g] = __builtin_amdgcn_mfma_f32_16x16x32_bf16(Ah, Bh[g], acc[m][g], 0, 0, 0);
                    acc[m][g] = __builtin_amdgcn_mfma_f32_16x16x32_bf16(Ah, Bl[g], acc[m][g], 0, 0, 0);
                    acc[m][g] = __builtin_amdgcn_mfma_f32_16x16x32_bf16(Al, Bh[g], acc[m][g], 0, 0, 0);
                }
            }
        }

        __syncthreads();   // all A-reads of Hhi/Hlo done
        if (l < 3) {
            #pragma unroll
            for (int m = 0; m < 4; m++) {
                #pragma unroll
                for (int r = 0; r < 4; r++) {
                    float cs = hsig(acc[m][0][r]) * tanh_fast(acc[m][1][r]);
                    float h  = hsig(acc[m][2][r]) * tanh_fast(cs);
                    int p = m * 16 + quad * 4 + r;
                    unsigned short hh = f2bf_rn(h);
                    Hhi[p][n] = hh;
                    Hlo[p][n] = f2bf_rn(h - bf2f(hh));
                }
            }
            __syncthreads();
        } else {
            #pragma unroll
            for (int m = 0; m < 4; m++) {
                #pragma unroll
                for (int r = 0; r < 4; r++) {
                    float cs = hsig(acc[m][0][r]) * tanh_fast(acc[m][1][r]);
                    float h  = hsig(acc[m][2][r]) * tanh_fast(cs);
                    int p = pbase + m * 16 + quad * 4 + r;
                    h4[(size_t)p * 64 + n] = h;
                }
            }
        }
    }
}

// Partial GEMM: C[b][j] = sum_k A[b][k]*Bw[k][j]; K split over 512 blocks.
__global__ __launch_bounds__(256) void d1_partial(
    const float* __restrict__ A, const float* __restrict__ Bw,
    float* __restrict__ part)
{
    __shared__ float As[64][68];
    __shared__ float Bs[64][64];
    const int t = threadIdx.x;
    const int kb = blockIdx.x;
    const int tx = t & 15, ty = t >> 4;

    float acc[4][4];
    #pragma unroll
    for (int i = 0; i < 4; i++)
        #pragma unroll
        for (int j = 0; j < 4; j++) acc[i][j] = 0.0f;

    for (int kc = 0; kc < 4; kc++) {
        const int k0 = kb * 256 + kc * 64;
        __syncthreads();
        #pragma unroll
        for (int i = 0; i < 16; i++) {
            int b  = (t >> 6) + 4 * i;
            int kk = t & 63;
            As[kk][b] = A[(size_t)b * 131072 + k0 + kk];
        }
        #pragma unroll
        for (int k = 0; k < 4; k++) {
            int idx4 = t + k * 256;
            int kk = idx4 >> 4;
            int j4 = (idx4 & 15) * 4;
            *(float4*)&Bs[kk][j4] = *(const float4*)(Bw + (size_t)(k0 + kk) * 64 + j4);
        }
        __syncthreads();
        #pragma unroll 8
        for (int kk = 0; kk < 64; kk++) {
            float4 av = *(const float4*)&As[kk][4 * ty];
            float4 bv = *(const float4*)&Bs[kk][4 * tx];
            const float* ap = (const float*)&av;
            const float* bp = (const float*)&bv;
            #pragma unroll
            for (int i = 0; i < 4; i++)
                #pragma unroll
                for (int j = 0; j < 4; j++)
                    acc[i][j] = fmaf(ap[i], bp[j], acc[i][j]);
        }
    }
    float* dst = part + (size_t)kb * 4096;
    #pragma unroll
    for (int i = 0; i < 4; i++)
        #pragma unroll
        for (int j = 0; j < 4; j++)
            dst[(4 * ty + i) * 64 + 4 * tx + j] = acc[i][j];
}

// Reduce 512 partials, + D1b, relu, dot with D2w, + D2b. 64 blocks x 1024.
__global__ __launch_bounds__(1024) void d1_reduce(
    const float* __restrict__ part, const float* __restrict__ D1b,
    const float* __restrict__ D2w, const float* __restrict__ D2b,
    float* __restrict__ out)
{
    __shared__ float red[16][64];
    const int b = blockIdx.x;
    const int t = threadIdx.x;
    const int j = t & 63, s = t >> 6;
    float acc = 0.0f;
    #pragma unroll 4
    for (int m = 0; m < 32; m++)
        acc += part[(size_t)(s + 16 * m) * 4096 + b * 64 + j];
    red[s][j] = acc;
    __syncthreads();
    if (t < 64) {
        float v = D1b[t];
        #pragma unroll
        for (int s2 = 0; s2 < 16; s2++) v += red[s2][t];
        v = fmaxf(v, 0.0f) * D2w[t];
        #pragma unroll
        for (int off = 32; off > 0; off >>= 1)
            v += __shfl_down(v, off, 64);
        if (t == 0) out[b] = v + D2b[0];
    }
}

extern "C" void kernel_launch(void* const* d_in, const int* in_sizes, int n_in,
                              void* d_out, int out_size, void* d_ws, size_t ws_size,
                              hipStream_t stream) {
    (void)in_sizes; (void)n_in; (void)out_size; (void)ws_size;
    const float* x   = (const float*)d_in[0];
    const float* W1x = (const float*)d_in[1];
    const float* b1  = (const float*)d_in[3];
    const float* W2x = (const float*)d_in[4];
    const float* b2  = (const float*)d_in[6];
    const float* W3x = (const float*)d_in[7];
    const float* b3  = (const float*)d_in[9];
    const float* W4x = (const float*)d_in[10];
    const float* b4  = (const float*)d_in[12];
    const float* D1w = (const float*)d_in[13];
    const float* D1b = (const float*)d_in[14];
    const float* D2w = (const float*)d_in[15];
    const float* D2b = (const float*)d_in[16];
    float* out = (float*)d_out;

    float* h4   = (float*)d_ws;                       // 32 MB
    float* part = h4 + (size_t)POS * 64;              // 8 MB
    unsigned short* WT = (unsigned short*)(part + 512 * 4096);  // 384 KB

    prep_w<<<dim3(12), dim3(256), 0, stream>>>(W1x, W2x, W3x, W4x, WT);
    fused_mfma<<<dim3(POS / 64), dim3(256), 0, stream>>>(x, WT, b1, b2, b3, b4, h4);
    d1_partial<<<dim3(512), dim3(256), 0, stream>>>(h4, D1w, part);
    d1_reduce<<<dim3(64), dim3(1024), 0, stream>>>(part, D1b, D2w, D2b, out);
}

// Round 4
// 213.209 us; speedup vs baseline: 2.0293x; 1.0310x over previous
//
#include <hip/hip_runtime.h>

// Problem collapse: T=1, H=1, h0=c0=0 => Wh/f-gate dead; conv => pointwise
// matmul with Wx[(kh-1)//2,0,:,:]. 4 layers fused (split-bf16 MFMA,
// hi*hi+hi*lo+lo*hi ~ 2^-18 rel err), h4 emitted as split-bf16 planes.
// D1 GEMM also split-bf16 MFMA (D1w converted inline), 2-stage reduce + D2.

#define POS 131072

typedef __attribute__((ext_vector_type(8))) short bf16x8;
typedef __attribute__((ext_vector_type(4))) float f32x4;

__device__ __forceinline__ unsigned short f2bf_rn(float f) {
    unsigned u = __float_as_uint(f);
    u += 0x7FFF + ((u >> 16) & 1);
    return (unsigned short)(u >> 16);
}
__device__ __forceinline__ float bf2f(unsigned short h) {
    return __uint_as_float(((unsigned)h) << 16);
}
__device__ __forceinline__ float hsig(float x) {
    return fminf(fmaxf(fmaf(x, 0.2f, 0.5f), 0.0f), 1.0f);
}
// Branch-free tanh: abs err ~2e-7 (v_exp + v_rcp, no cancellation blowup
// since 1 - 2/(e^2x+1) keeps ABSOLUTE error at ~ulp of 1).
__device__ __forceinline__ float tanh_e(float x) {
    float t = __expf(2.0f * x);
    return 1.0f - __fdividef(2.0f, t + 1.0f);
}

// Layer weights -> transposed split-bf16: per layer [hi:192x64][lo:192x64],
// row = g*64 + n. Grid 12 = 4 layers x 3 gates.
__global__ __launch_bounds__(256) void prep_w(
    const float* __restrict__ W1, const float* __restrict__ W2,
    const float* __restrict__ W3, const float* __restrict__ W4,
    unsigned short* __restrict__ WT)
{
    const int bid = blockIdx.x;
    const int ll = bid / 3;
    const int g  = bid - ll * 3;
    const float* W = (ll == 0) ? (W1 + 4 * 16384) :
                     (ll == 1) ? (W2 + 2 * 16384) :
                     (ll == 2) ? (W3 + 4 * 16384) : (W4 + 2 * 16384);
    const int gofs = (g == 0) ? 0 : ((g == 1) ? 128 : 192);
    unsigned short* hi = WT + ll * (2 * 192 * 64) + (g * 64) * 64;
    unsigned short* lo = hi + 192 * 64;
    const int n  = threadIdx.x & 63;
    const int c0 = threadIdx.x >> 6;
    #pragma unroll
    for (int cc = 0; cc < 16; cc++) {
        int c = cc * 4 + c0;
        float w = W[c * 256 + gofs + n];
        unsigned short h = f2bf_rn(w);
        hi[n * 64 + c] = h;
        lo[n * 64 + c] = f2bf_rn(w - bf2f(h));
    }
}

// Fused 4-layer gated pointwise stack, split-bf16 MFMA 16x16x32.
// Block = 64 positions, 4 waves; wave w owns output channels 16w..16w+15.
__global__ __launch_bounds__(256, 4) void fused_mfma(
    const float* __restrict__ x,
    const unsigned short* __restrict__ WT,
    const float* __restrict__ B1, const float* __restrict__ B2,
    const float* __restrict__ B3, const float* __restrict__ B4,
    unsigned short* __restrict__ h4hi, unsigned short* __restrict__ h4lo)
{
    __shared__ unsigned short Hhi[64][72];   // stride 72 shorts = 144 B (16-mult)
    __shared__ unsigned short Hlo[64][72];

    const int t = threadIdx.x;
    const int lane = t & 63;
    const int w = t >> 6;
    const int tx = lane & 15;
    const int quad = lane >> 4;
    const int n = 16 * w + tx;
    const int pbase = blockIdx.x * 64;

    // Stage x -> split-bf16 LDS (transposed per-position rows).
    {
        const float4* xv = (const float4*)(x + (size_t)pbase * 64);
        #pragma unroll
        for (int k = 0; k < 4; k++) {
            int lin4 = t + k * 256;
            int p = lin4 >> 4;
            int c0 = (lin4 & 15) * 4;
            float4 v = xv[lin4];
            const float* vp = (const float*)&v;
            unsigned short h0 = f2bf_rn(vp[0]), h1 = f2bf_rn(vp[1]);
            unsigned short h2 = f2bf_rn(vp[2]), h3 = f2bf_rn(vp[3]);
            unsigned hh01 = (unsigned)h0 | ((unsigned)h1 << 16);
            unsigned hh23 = (unsigned)h2 | ((unsigned)h3 << 16);
            unsigned ll01 = (unsigned)f2bf_rn(vp[0] - bf2f(h0)) |
                            ((unsigned)f2bf_rn(vp[1] - bf2f(h1)) << 16);
            unsigned ll23 = (unsigned)f2bf_rn(vp[2] - bf2f(h2)) |
                            ((unsigned)f2bf_rn(vp[3] - bf2f(h3)) << 16);
            *(uint2*)&Hhi[p][c0] = make_uint2(hh01, hh23);
            *(uint2*)&Hlo[p][c0] = make_uint2(ll01, ll23);
        }
    }
    __syncthreads();

    #pragma unroll 1
    for (int l = 0; l < 4; l++) {
        const unsigned short* wl = WT + l * (2 * 192 * 64);
        const float* Bb = (l == 0) ? B1 : (l == 1) ? B2 : (l == 2) ? B3 : B4;
        const float bi = Bb[n];
        const float bg = Bb[128 + n];
        const float bo = Bb[192 + n];

        f32x4 acc[4][3];
        #pragma unroll
        for (int m = 0; m < 4; m++) {
            acc[m][0] = (f32x4){bi, bi, bi, bi};
            acc[m][1] = (f32x4){bg, bg, bg, bg};
            acc[m][2] = (f32x4){bo, bo, bo, bo};
        }

        #pragma unroll
        for (int ks = 0; ks < 2; ks++) {
            bf16x8 Bh[3], Bl[3];
            #pragma unroll
            for (int g = 0; g < 3; g++) {
                const unsigned short* bp = wl + (g * 64 + n) * 64 + ks * 32 + quad * 8;
                Bh[g] = *(const bf16x8*)bp;
                Bl[g] = *(const bf16x8*)(bp + 192 * 64);
            }
            #pragma unroll
            for (int m = 0; m < 4; m++) {
                bf16x8 Ah = *(const bf16x8*)&Hhi[m * 16 + tx][ks * 32 + quad * 8];
                bf16x8 Al = *(const bf16x8*)&Hlo[m * 16 + tx][ks * 32 + quad * 8];
                #pragma unroll
                for (int g = 0; g < 3; g++) {
                    acc[m][g] = __builtin_amdgcn_mfma_f32_16x16x32_bf16(Ah, Bh[g], acc[m][g], 0, 0, 0);
                    acc[m][g] = __builtin_amdgcn_mfma_f32_16x16x32_bf16(Ah, Bl[g], acc[m][g], 0, 0, 0);
                    acc[m][g] = __builtin_amdgcn_mfma_f32_16x16x32_bf16(Al, Bh[g], acc[m][g], 0, 0, 0);
                }
            }
        }

        __syncthreads();   // all A-reads of Hhi/Hlo + Ws reads done
        #pragma unroll
        for (int m = 0; m < 4; m++) {
            #pragma unroll
            for (int r = 0; r < 4; r++) {
                float cs = hsig(acc[m][0][r]) * tanh_e(acc[m][1][r]);
                float h  = hsig(acc[m][2][r]) * tanh_e(cs);
                int p = m * 16 + quad * 4 + r;
                unsigned short hh = f2bf_rn(h);
                Hhi[p][n] = hh;
                Hlo[p][n] = f2bf_rn(h - bf2f(hh));
            }
        }
        __syncthreads();
    }

    // Coalesced copy-out of split-bf16 h4 planes.
    #pragma unroll
    for (int i = 0; i < 2; i++) {
        int lin8 = t + i * 256;        // 8-short chunk id (512 total)
        int p = lin8 >> 3;
        int c0 = (lin8 & 7) * 8;
        uint4 vh = *(const uint4*)&Hhi[p][c0];
        uint4 vl = *(const uint4*)&Hlo[p][c0];
        size_t g = (size_t)(pbase + p) * 64 + c0;
        *(uint4*)(h4hi + g) = vh;
        *(uint4*)(h4lo + g) = vl;
    }
}

// D1 partial GEMM via split-bf16 MFMA. Block = K-chunk of 64.
// A = flat (64 batches x 131072) already split-bf16; B = D1w fp32, converted inline.
__global__ __launch_bounds__(256) void d1_mfma(
    const unsigned short* __restrict__ Ahig, const unsigned short* __restrict__ Alog,
    const float* __restrict__ Bw, float* __restrict__ part)
{
    __shared__ unsigned short Ahi[64][72], Alo[64][72];   // [m][k]
    __shared__ unsigned short Bhi[64][66], Blo[64][66];   // [k][j], stride 66: 2-way banks
    const int t = threadIdx.x;
    const int kb = blockIdx.x;
    const int lane = t & 63, w = t >> 6;
    const int tx = lane & 15, quad = lane >> 4;
    const int n = 16 * w + tx;

    // Stage A (64 x 64 shorts per plane).
    #pragma unroll
    for (int i = 0; i < 2; i++) {
        int lin8 = t + i * 256;
        int row = lin8 >> 3;
        int c0 = (lin8 & 7) * 8;
        size_t g = (size_t)row * 131072 + (size_t)kb * 64 + c0;
        *(uint4*)&Ahi[row][c0] = *(const uint4*)(Ahig + g);
        *(uint4*)&Alo[row][c0] = *(const uint4*)(Alog + g);
    }
    // Stage B: fp32 -> split bf16.
    #pragma unroll
    for (int i = 0; i < 4; i++) {
        int lin4 = t + i * 256;
        int k = lin4 >> 4;
        int j0 = (lin4 & 15) * 4;
        float4 v = *(const float4*)(Bw + (size_t)(kb * 64 + k) * 64 + j0);
        const float* vp = (const float*)&v;
        unsigned short h0 = f2bf_rn(vp[0]), h1 = f2bf_rn(vp[1]);
        unsigned short h2 = f2bf_rn(vp[2]), h3 = f2bf_rn(vp[3]);
        *(unsigned*)&Bhi[k][j0]     = (unsigned)h0 | ((unsigned)h1 << 16);
        *(unsigned*)&Bhi[k][j0 + 2] = (unsigned)h2 | ((unsigned)h3 << 16);
        *(unsigned*)&Blo[k][j0]     = (unsigned)f2bf_rn(vp[0] - bf2f(h0)) |
                                      ((unsigned)f2bf_rn(vp[1] - bf2f(h1)) << 16);
        *(unsigned*)&Blo[k][j0 + 2] = (unsigned)f2bf_rn(vp[2] - bf2f(h2)) |
                                      ((unsigned)f2bf_rn(vp[3] - bf2f(h3)) << 16);
    }
    __syncthreads();

    f32x4 acc[4];
    #pragma unroll
    for (int m = 0; m < 4; m++) acc[m] = (f32x4){0.0f, 0.0f, 0.0f, 0.0f};

    #pragma unroll
    for (int ks = 0; ks < 2; ks++) {
        bf16x8 Bh, Bl;
        #pragma unroll
        for (int jj = 0; jj < 8; jj++) {
            int k = ks * 32 + quad * 8 + jj;
            Bh[jj] = (short)Bhi[k][n];
            Bl[jj] = (short)Blo[k][n];
        }
        #pragma unroll
        for (int m = 0; m < 4; m++) {
            bf16x8 Ah = *(const bf16x8*)&Ahi[m * 16 + tx][ks * 32 + quad * 8];
            bf16x8 Al = *(const bf16x8*)&Alo[m * 16 + tx][ks * 32 + quad * 8];
            acc[m] = __builtin_amdgcn_mfma_f32_16x16x32_bf16(Ah, Bh, acc[m], 0, 0, 0);
            acc[m] = __builtin_amdgcn_mfma_f32_16x16x32_bf16(Ah, Bl, acc[m], 0, 0, 0);
            acc[m] = __builtin_amdgcn_mfma_f32_16x16x32_bf16(Al, Bh, acc[m], 0, 0, 0);
        }
    }

    float* dst = part + (size_t)kb * 4096;
    #pragma unroll
    for (int m = 0; m < 4; m++)
        #pragma unroll
        for (int r = 0; r < 4; r++)
            dst[(m * 16 + quad * 4 + r) * 64 + n] = acc[m][r];
}

// Stage-1 reduce: 512 blocks = (b, g), each sums 256 K-chunks.
__global__ __launch_bounds__(256) void d1_reduce1(
    const float* __restrict__ part, float* __restrict__ part2)
{
    __shared__ float red[4][64];
    const int b = blockIdx.x >> 3;
    const int g = blockIdx.x & 7;
    const int t = threadIdx.x;
    const int j = t & 63, s = t >> 6;
    float acc = 0.0f;
    #pragma unroll 4
    for (int m = 0; m < 64; m++)
        acc += part[(size_t)(g * 256 + s + 4 * m) * 4096 + b * 64 + j];
    red[s][j] = acc;
    __syncthreads();
    if (t < 64)
        part2[(size_t)(b * 8 + g) * 64 + t] =
            red[0][t] + red[1][t] + red[2][t] + red[3][t];
}

// Stage-2: final sum + D1b + relu + dot D2w + D2b.
__global__ __launch_bounds__(64) void d1_reduce2(
    const float* __restrict__ part2, const float* __restrict__ D1b,
    const float* __restrict__ D2w, const float* __restrict__ D2b,
    float* __restrict__ out)
{
    const int b = blockIdx.x;
    const int j = threadIdx.x;
    float v = D1b[j];
    #pragma unroll
    for (int g = 0; g < 8; g++) v += part2[(size_t)(b * 8 + g) * 64 + j];
    v = fmaxf(v, 0.0f) * D2w[j];
    #pragma unroll
    for (int off = 32; off > 0; off >>= 1)
        v += __shfl_down(v, off, 64);
    if (j == 0) out[b] = v + D2b[0];
}

extern "C" void kernel_launch(void* const* d_in, const int* in_sizes, int n_in,
                              void* d_out, int out_size, void* d_ws, size_t ws_size,
                              hipStream_t stream) {
    (void)in_sizes; (void)n_in; (void)out_size; (void)ws_size;
    const float* x   = (const float*)d_in[0];
    const float* W1x = (const float*)d_in[1];
    const float* b1  = (const float*)d_in[3];
    const float* W2x = (const float*)d_in[4];
    const float* b2  = (const float*)d_in[6];
    const float* W3x = (const float*)d_in[7];
    const float* b3  = (const float*)d_in[9];
    const float* W4x = (const float*)d_in[10];
    const float* b4  = (const float*)d_in[12];
    const float* D1w = (const float*)d_in[13];
    const float* D1b = (const float*)d_in[14];
    const float* D2w = (const float*)d_in[15];
    const float* D2b = (const float*)d_in[16];
    float* out = (float*)d_out;

    unsigned short* h4hi = (unsigned short*)d_ws;            // 16 MB
    unsigned short* h4lo = h4hi + (size_t)POS * 64;          // 16 MB
    float* part  = (float*)(h4lo + (size_t)POS * 64);        // 2048*4096*4 = 32 MB
    float* part2 = part + (size_t)2048 * 4096;               // 128 KB
    unsigned short* WT = (unsigned short*)(part2 + 512 * 64);// 384 KB

    prep_w<<<dim3(12), dim3(256), 0, stream>>>(W1x, W2x, W3x, W4x, WT);
    fused_mfma<<<dim3(POS / 64), dim3(256), 0, stream>>>(
        x, WT, b1, b2, b3, b4, h4hi, h4lo);
    d1_mfma<<<dim3(2048), dim3(256), 0, stream>>>(h4hi, h4lo, D1w, part);
    d1_reduce1<<<dim3(512), dim3(256), 0, stream>>>(part, part2);
    d1_reduce2<<<dim3(64), dim3(64), 0, stream>>>(part2, D1b, D2w, D2b, out);
}

// Round 5
// 201.615 us; speedup vs baseline: 2.1460x; 1.0575x over previous
//
#include <hip/hip_runtime.h>

// Problem collapse: T=1, H=1, h0=c0=0 => Wh/f-gate dead; conv => pointwise
// matmul with Wx[(kh-1)//2,0,:,:]. 4 layers fused (split-bf16 MFMA,
// hi*hi+hi*lo+lo*hi ~ 2^-18 rel err), h4 emitted as split-bf16 planes.
// D1 GEMM split-bf16 MFMA (K=256/block, reg accumulation), 1-kernel reduce+D2.

#define POS 131072
#define SH 80   // LDS row stride (shorts): 16B-aligned; quad p-offsets land on
                // distinct bank octets -> conflict-free epilogue u16 writes

typedef __attribute__((ext_vector_type(8))) short bf16x8;
typedef __attribute__((ext_vector_type(4))) float f32x4;

__device__ __forceinline__ unsigned short f2bf_rn(float f) {
    unsigned u = __float_as_uint(f);
    u += 0x7FFF + ((u >> 16) & 1);
    return (unsigned short)(u >> 16);
}
__device__ __forceinline__ float bf2f(unsigned short h) {
    return __uint_as_float(((unsigned)h) << 16);
}
__device__ __forceinline__ float hsig(float x) {
    return fminf(fmaxf(fmaf(x, 0.2f, 0.5f), 0.0f), 1.0f);
}
__device__ __forceinline__ float tanh_e(float x) {
    float t = __expf(2.0f * x);
    return 1.0f - __fdividef(2.0f, t + 1.0f);
}

// Layer weights -> transposed split-bf16: per layer [hi:192x64][lo:192x64],
// row = g*64 + n. Grid 12 = 4 layers x 3 gates.
__global__ __launch_bounds__(256) void prep_w(
    const float* __restrict__ W1, const float* __restrict__ W2,
    const float* __restrict__ W3, const float* __restrict__ W4,
    unsigned short* __restrict__ WT)
{
    const int bid = blockIdx.x;
    const int ll = bid / 3;
    const int g  = bid - ll * 3;
    const float* W = (ll == 0) ? (W1 + 4 * 16384) :
                     (ll == 1) ? (W2 + 2 * 16384) :
                     (ll == 2) ? (W3 + 4 * 16384) : (W4 + 2 * 16384);
    const int gofs = (g == 0) ? 0 : ((g == 1) ? 128 : 192);
    unsigned short* hi = WT + ll * (2 * 192 * 64) + (g * 64) * 64;
    unsigned short* lo = hi + 192 * 64;
    const int n  = threadIdx.x & 63;
    const int c0 = threadIdx.x >> 6;
    #pragma unroll
    for (int cc = 0; cc < 16; cc++) {
        int c = cc * 4 + c0;
        float w = W[c * 256 + gofs + n];
        unsigned short h = f2bf_rn(w);
        hi[n * 64 + c] = h;
        lo[n * 64 + c] = f2bf_rn(w - bf2f(h));
    }
}

// Fused 4-layer gated pointwise stack, split-bf16 MFMA 16x16x32.
// Block = 64 positions, 4 waves; wave w owns output channels 16w..16w+15.
// B-frags prefetched one layer ahead (loads overlap epilogue + barriers).
__global__ __launch_bounds__(256, 4) void fused_mfma(
    const float* __restrict__ x,
    const unsigned short* __restrict__ WT,
    const float* __restrict__ B1, const float* __restrict__ B2,
    const float* __restrict__ B3, const float* __restrict__ B4,
    unsigned short* __restrict__ h4hi, unsigned short* __restrict__ h4lo)
{
    __shared__ unsigned short Hhi[64][SH];
    __shared__ unsigned short Hlo[64][SH];

    const int t = threadIdx.x;
    const int lane = t & 63;
    const int w = t >> 6;
    const int tx = lane & 15;
    const int quad = lane >> 4;
    const int n = 16 * w + tx;
    const int pbase = blockIdx.x * 64;

    bf16x8 Bh[2][3], Bl[2][3];
    auto loadB = [&](int l) {
        const unsigned short* wl = WT + l * (2 * 192 * 64);
        #pragma unroll
        for (int ks = 0; ks < 2; ks++)
            #pragma unroll
            for (int g = 0; g < 3; g++) {
                const unsigned short* bp = wl + (g * 64 + n) * 64 + ks * 32 + quad * 8;
                Bh[ks][g] = *(const bf16x8*)bp;
                Bl[ks][g] = *(const bf16x8*)(bp + 192 * 64);
            }
    };

    loadB(0);   // overlaps x staging

    // Stage x -> split-bf16 LDS (transposed per-position rows).
    {
        const float4* xv = (const float4*)(x + (size_t)pbase * 64);
        #pragma unroll
        for (int k = 0; k < 4; k++) {
            int lin4 = t + k * 256;
            int p = lin4 >> 4;
            int c0 = (lin4 & 15) * 4;
            float4 v = xv[lin4];
            const float* vp = (const float*)&v;
            unsigned short h0 = f2bf_rn(vp[0]), h1 = f2bf_rn(vp[1]);
            unsigned short h2 = f2bf_rn(vp[2]), h3 = f2bf_rn(vp[3]);
            unsigned hh01 = (unsigned)h0 | ((unsigned)h1 << 16);
            unsigned hh23 = (unsigned)h2 | ((unsigned)h3 << 16);
            unsigned ll01 = (unsigned)f2bf_rn(vp[0] - bf2f(h0)) |
                            ((unsigned)f2bf_rn(vp[1] - bf2f(h1)) << 16);
            unsigned ll23 = (unsigned)f2bf_rn(vp[2] - bf2f(h2)) |
                            ((unsigned)f2bf_rn(vp[3] - bf2f(h3)) << 16);
            *(uint2*)&Hhi[p][c0] = make_uint2(hh01, hh23);
            *(uint2*)&Hlo[p][c0] = make_uint2(ll01, ll23);
        }
    }
    __syncthreads();

    #pragma unroll 1
    for (int l = 0; l < 4; l++) {
        const float* Bb = (l == 0) ? B1 : (l == 1) ? B2 : (l == 2) ? B3 : B4;
        const float bi = Bb[n];
        const float bg = Bb[128 + n];
        const float bo = Bb[192 + n];

        f32x4 acc[4][3];
        #pragma unroll
        for (int m = 0; m < 4; m++) {
            acc[m][0] = (f32x4){bi, bi, bi, bi};
            acc[m][1] = (f32x4){bg, bg, bg, bg};
            acc[m][2] = (f32x4){bo, bo, bo, bo};
        }

        #pragma unroll
        for (int ks = 0; ks < 2; ks++)
            #pragma unroll
            for (int m = 0; m < 4; m++) {
                bf16x8 Ah = *(const bf16x8*)&Hhi[m * 16 + tx][ks * 32 + quad * 8];
                bf16x8 Al = *(const bf16x8*)&Hlo[m * 16 + tx][ks * 32 + quad * 8];
                #pragma unroll
                for (int g = 0; g < 3; g++) {
                    acc[m][g] = __builtin_amdgcn_mfma_f32_16x16x32_bf16(Ah, Bh[ks][g], acc[m][g], 0, 0, 0);
                    acc[m][g] = __builtin_amdgcn_mfma_f32_16x16x32_bf16(Ah, Bl[ks][g], acc[m][g], 0, 0, 0);
                    acc[m][g] = __builtin_amdgcn_mfma_f32_16x16x32_bf16(Al, Bh[ks][g], acc[m][g], 0, 0, 0);
                }
            }

        // Prefetch next layer's B (safe: current B consumed by MFMAs above).
        if (l < 3) loadB(l + 1);

        // Epilogue compute (acc-only) overlaps the prefetch latency.
        float hv[4][4];
        #pragma unroll
        for (int m = 0; m < 4; m++)
            #pragma unroll
            for (int r = 0; r < 4; r++) {
                float cs = hsig(acc[m][0][r]) * tanh_e(acc[m][1][r]);
                hv[m][r] = hsig(acc[m][2][r]) * tanh_e(cs);
            }

        __syncthreads();   // all A-reads of Hhi/Hlo done -> safe to overwrite
        #pragma unroll
        for (int m = 0; m < 4; m++)
            #pragma unroll
            for (int r = 0; r < 4; r++) {
                int p = m * 16 + quad * 4 + r;
                unsigned short hh = f2bf_rn(hv[m][r]);
                Hhi[p][n] = hh;
                Hlo[p][n] = f2bf_rn(hv[m][r] - bf2f(hh));
            }
        __syncthreads();
    }

    // Coalesced copy-out of split-bf16 h4 planes.
    #pragma unroll
    for (int i = 0; i < 2; i++) {
        int lin8 = t + i * 256;
        int p = lin8 >> 3;
        int c0 = (lin8 & 7) * 8;
        uint4 vh = *(const uint4*)&Hhi[p][c0];
        uint4 vl = *(const uint4*)&Hlo[p][c0];
        size_t g = (size_t)(pbase + p) * 64 + c0;
        *(uint4*)(h4hi + g) = vh;
        *(uint4*)(h4lo + g) = vl;
    }
}

// D1 partial GEMM, split-bf16 MFMA. Block = K-chunk of 256 (4 sub-chunks of
// 64, register accumulation). A = flat (64 x 131072) split-bf16; B = D1w
// fp32 converted inline.
__global__ __launch_bounds__(256) void d1_mfma(
    const unsigned short* __restrict__ Ahig, const unsigned short* __restrict__ Alog,
    const float* __restrict__ Bw, float* __restrict__ part)
{
    __shared__ unsigned short Ahi[64][SH], Alo[64][SH];
    __shared__ unsigned short Bhi[64][66], Blo[64][66];
    const int t = threadIdx.x;
    const int kb = blockIdx.x;
    const int lane = t & 63, w = t >> 6;
    const int tx = lane & 15, quad = lane >> 4;
    const int n = 16 * w + tx;

    f32x4 acc[4];
    #pragma unroll
    for (int m = 0; m < 4; m++) acc[m] = (f32x4){0.0f, 0.0f, 0.0f, 0.0f};

    #pragma unroll 1
    for (int sub = 0; sub < 4; sub++) {
        const int k0 = kb * 256 + sub * 64;
        if (sub) __syncthreads();
        // Stage A (64 x 64 shorts per plane).
        #pragma unroll
        for (int i = 0; i < 2; i++) {
            int lin8 = t + i * 256;
            int row = lin8 >> 3;
            int c0 = (lin8 & 7) * 8;
            size_t g = (size_t)row * 131072 + k0 + c0;
            *(uint4*)&Ahi[row][c0] = *(const uint4*)(Ahig + g);
            *(uint4*)&Alo[row][c0] = *(const uint4*)(Alog + g);
        }
        // Stage B: fp32 -> split bf16 ([k][j], conflict-free uint writes).
        #pragma unroll
        for (int i = 0; i < 4; i++) {
            int lin4 = t + i * 256;
            int k = lin4 >> 4;
            int j0 = (lin4 & 15) * 4;
            float4 v = *(const float4*)(Bw + (size_t)(k0 + k) * 64 + j0);
            const float* vp = (const float*)&v;
            unsigned short h0 = f2bf_rn(vp[0]), h1 = f2bf_rn(vp[1]);
            unsigned short h2 = f2bf_rn(vp[2]), h3 = f2bf_rn(vp[3]);
            *(unsigned*)&Bhi[k][j0]     = (unsigned)h0 | ((unsigned)h1 << 16);
            *(unsigned*)&Bhi[k][j0 + 2] = (unsigned)h2 | ((unsigned)h3 << 16);
            *(unsigned*)&Blo[k][j0]     = (unsigned)f2bf_rn(vp[0] - bf2f(h0)) |
                                          ((unsigned)f2bf_rn(vp[1] - bf2f(h1)) << 16);
            *(unsigned*)&Blo[k][j0 + 2] = (unsigned)f2bf_rn(vp[2] - bf2f(h2)) |
                                          ((unsigned)f2bf_rn(vp[3] - bf2f(h3)) << 16);
        }
        __syncthreads();

        #pragma unroll
        for (int ks = 0; ks < 2; ks++) {
            bf16x8 Bh, Bl;
            #pragma unroll
            for (int jj = 0; jj < 8; jj++) {
                int k = ks * 32 + quad * 8 + jj;
                Bh[jj] = (short)Bhi[k][n];
                Bl[jj] = (short)Blo[k][n];
            }
            #pragma unroll
            for (int m = 0; m < 4; m++) {
                bf16x8 Ah = *(const bf16x8*)&Ahi[m * 16 + tx][ks * 32 + quad * 8];
                bf16x8 Al = *(const bf16x8*)&Alo[m * 16 + tx][ks * 32 + quad * 8];
                acc[m] = __builtin_amdgcn_mfma_f32_16x16x32_bf16(Ah, Bh, acc[m], 0, 0, 0);
                acc[m] = __builtin_amdgcn_mfma_f32_16x16x32_bf16(Ah, Bl, acc[m], 0, 0, 0);
                acc[m] = __builtin_amdgcn_mfma_f32_16x16x32_bf16(Al, Bh, acc[m], 0, 0, 0);
            }
        }
    }

    float* dst = part + (size_t)kb * 4096;
    #pragma unroll
    for (int m = 0; m < 4; m++)
        #pragma unroll
        for (int r = 0; r < 4; r++)
            dst[(m * 16 + quad * 4 + r) * 64 + n] = acc[m][r];
}

// Single reduce: sum 512 tiles + D1b, relu, dot D2w, + D2b. 64 blocks x 1024.
__global__ __launch_bounds__(1024) void d1_reduce(
    const float* __restrict__ part, const float* __restrict__ D1b,
    const float* __restrict__ D2w, const float* __restrict__ D2b,
    float* __restrict__ out)
{
    __shared__ float red[16][64];
    const int b = blockIdx.x;
    const int t = threadIdx.x;
    const int j = t & 63, s = t >> 6;
    float acc = 0.0f;
    #pragma unroll 4
    for (int m = 0; m < 32; m++)
        acc += part[(size_t)(s + 16 * m) * 4096 + b * 64 + j];
    red[s][j] = acc;
    __syncthreads();
    if (t < 64) {
        float v = D1b[t];
        #pragma unroll
        for (int s2 = 0; s2 < 16; s2++) v += red[s2][t];
        v = fmaxf(v, 0.0f) * D2w[t];
        #pragma unroll
        for (int off = 32; off > 0; off >>= 1)
            v += __shfl_down(v, off, 64);
        if (t == 0) out[b] = v + D2b[0];
    }
}

extern "C" void kernel_launch(void* const* d_in, const int* in_sizes, int n_in,
                              void* d_out, int out_size, void* d_ws, size_t ws_size,
                              hipStream_t stream) {
    (void)in_sizes; (void)n_in; (void)out_size; (void)ws_size;
    const float* x   = (const float*)d_in[0];
    const float* W1x = (const float*)d_in[1];
    const float* b1  = (const float*)d_in[3];
    const float* W2x = (const float*)d_in[4];
    const float* b2  = (const float*)d_in[6];
    const float* W3x = (const float*)d_in[7];
    const float* b3  = (const float*)d_in[9];
    const float* W4x = (const float*)d_in[10];
    const float* b4  = (const float*)d_in[12];
    const float* D1w = (const float*)d_in[13];
    const float* D1b = (const float*)d_in[14];
    const float* D2w = (const float*)d_in[15];
    const float* D2b = (const float*)d_in[16];
    float* out = (float*)d_out;

    unsigned short* h4hi = (unsigned short*)d_ws;            // 16 MB
    unsigned short* h4lo = h4hi + (size_t)POS * 64;          // 16 MB
    float* part = (float*)(h4lo + (size_t)POS * 64);         // 512*4096*4 = 8 MB
    unsigned short* WT = (unsigned short*)(part + (size_t)512 * 4096);  // 384 KB

    prep_w<<<dim3(12), dim3(256), 0, stream>>>(W1x, W2x, W3x, W4x, WT);
    fused_mfma<<<dim3(POS / 64), dim3(256), 0, stream>>>(
        x, WT, b1, b2, b3, b4, h4hi, h4lo);
    d1_mfma<<<dim3(512), dim3(256), 0, stream>>>(h4hi, h4lo, D1w, part);
    d1_reduce<<<dim3(64), dim3(1024), 0, stream>>>(part, D1b, D2w, D2b, out);
}